// Round 1
// baseline (223.156 us; speedup 1.0000x reference)
//
#include <hip/hip_runtime.h>

#define NB 64
#define NA 256
#define NT 2048
#define NK 16

// Kernel 1: for each (b,t) column, compute argmax over atoms of thresholded x,
// write the validity mask output, and zero the feat output.
__global__ __launch_bounds__(256) void k1_argmax(
    const float* __restrict__ x, const float* __restrict__ thr_p,
    float* __restrict__ feat, float* __restrict__ mask,
    int* __restrict__ amax_idx, float* __restrict__ amax_val) {
    const float thr = thr_p[0];
    const int t = blockIdx.x * blockDim.x + threadIdx.x;   // 0..NT-1
    const int b = blockIdx.y;
    const float* xb = x + (size_t)b * NA * NT;
    float* fb = feat + (size_t)b * NA * NT;
    float* mb = mask + (size_t)b * NA * NT;

    float maxv = -1.0f;
    int maxi = 0;
    #pragma unroll 4
    for (int a = 0; a < NA; ++a) {
        const size_t off = (size_t)a * NT + t;
        const float v = xb[off];
        const bool valid = (v >= thr);          // invalid = x < thr (strict)
        mb[off] = valid ? 1.0f : 0.0f;
        fb[off] = 0.0f;
        const float vt = valid ? v : 0.0f;
        if (vt > maxv) { maxv = vt; maxi = a; } // strict > keeps lowest atom on ties
    }
    amax_idx[b * NT + t] = maxi;
    amax_val[b * NT + t] = maxv;                // 0 if column fully below threshold
}

// Kernel 2: one wave per (b,a) row. Candidates = times where atom a won the
// argmax with value > 0. Top-16 by value desc (tie -> lower t), then fill with
// smallest zero-valued t. Write indices (as float) and scatter 1.0s into feat.
__global__ __launch_bounds__(64) void k2_topk(
    const int* __restrict__ amax_idx, const float* __restrict__ amax_val,
    float* __restrict__ feat, float* __restrict__ idx_out) {
    __shared__ int   cand_t[NT];
    __shared__ float cand_v[NT];
    __shared__ int   sel[NK];

    const int lane = threadIdx.x;              // 0..63
    const int row  = blockIdx.x;               // b*NA + a
    const int b = row / NA;
    const int a = row % NA;
    const int*   ib = amax_idx + b * NT;
    const float* vb = amax_val + b * NT;

    // Build candidate list in ascending-t order via ballot + prefix popcount.
    int count = 0;
    for (int base = 0; base < NT; base += 64) {
        const int t = base + lane;
        const int   ai = ib[t];
        const float v  = vb[t];
        const bool pred = (ai == a) && (v > 0.0f);
        const unsigned long long m = __ballot(pred);
        if (pred) {
            const int pos = count + __popcll(m & ((1ull << lane) - 1ull));
            cand_t[pos] = t;
            cand_v[pos] = v;
        }
        count += (int)__popcll(m);
    }
    __syncthreads();

    // Selection: up to NK picks, value desc, tie -> lower t.
    const int nsel = (count < NK) ? count : NK;
    for (int k = 0; k < nsel; ++k) {
        float bv = -1.0f; int bt = 0x7fffffff; int bi = -1;
        for (int i = lane; i < count; i += 64) {
            const float v = cand_v[i];
            const int   t = cand_t[i];
            if (v > bv || (v == bv && t < bt)) { bv = v; bt = t; bi = i; }
        }
        #pragma unroll
        for (int off = 32; off > 0; off >>= 1) {
            const float ov = __shfl_down(bv, off);
            const int   ot = __shfl_down(bt, off);
            const int   oi = __shfl_down(bi, off);
            if (ov > bv || (ov == bv && ot < bt)) { bv = ov; bt = ot; bi = oi; }
        }
        bt = __shfl(bt, 0);
        bi = __shfl(bi, 0);
        if (lane == 0) { sel[k] = bt; cand_v[bi] = -1.0f; }
        __syncthreads();
    }

    // Zero-fill: smallest t not in the candidate set (cand_t ascending).
    if (lane == 0) {
        int k = nsel, ptr = 0, t = 0;
        while (k < NK) {
            if (ptr < count && cand_t[ptr] == t) { ++ptr; ++t; continue; }
            sel[k++] = t; ++t;
        }
    }
    __syncthreads();

    if (lane < NK) {
        const int t = sel[lane];
        idx_out[(size_t)row * NK + lane] = (float)t;
        feat[(size_t)row * NT + t] = 1.0f;
    }
}

extern "C" void kernel_launch(void* const* d_in, const int* in_sizes, int n_in,
                              void* d_out, int out_size, void* d_ws, size_t ws_size,
                              hipStream_t stream) {
    const float* x   = (const float*)d_in[0];
    const float* thr = (const float*)d_in[1];

    float* feat    = (float*)d_out;                       // [B,A,T]
    float* idx_out = feat + (size_t)NB * NA * NT;         // [B,A,K] (indices as float)
    float* mask    = idx_out + (size_t)NB * NA * NK;      // [B,A,T]

    int*   amax_idx = (int*)d_ws;                         // [B,T]
    float* amax_val = (float*)((char*)d_ws + sizeof(int) * (size_t)NB * NT);

    dim3 g1(NT / 256, NB);
    hipLaunchKernelGGL(k1_argmax, g1, dim3(256), 0, stream,
                       x, thr, feat, mask, amax_idx, amax_val);
    hipLaunchKernelGGL(k2_topk, dim3(NB * NA), dim3(64), 0, stream,
                       amax_idx, amax_val, feat, idx_out);
}